// Round 12
// baseline (175.466 us; speedup 1.0000x reference)
//
#include <hip/hip_runtime.h>
#include <stdint.h>

typedef unsigned short ushort_t;
typedef __bf16 bf16x8 __attribute__((ext_vector_type(8)));
typedef float f32x4 __attribute__((ext_vector_type(4)));

#define M_TOK 8192
#define K1 1024
#define N1 4096
#define K2 4160   /* 4096 (h) + 16 (probs/b2) + 48 zero-pad -> 65 K-steps of 64 */
#define N2 1024

template <int V> struct ic { static constexpr int value = V; };

__device__ __forceinline__ ushort_t f2bf(float f) {
  union { float f; unsigned u; } v; v.f = f;
  unsigned u = v.u;
  u += 0x7FFFu + ((u >> 16) & 1u);   // RNE; inputs finite
  return (ushort_t)(u >> 16);
}

__device__ __forceinline__ void gload16(const void* g, void* l) {
  __builtin_amdgcn_global_load_lds((__attribute__((address_space(1))) void*)g,
                                   (__attribute__((address_space(3))) void*)l,
                                   16, 0, 0);
}

// -------- merged prep: wprep (blocks 0..2303) + probs (2304..2815) ----------
// probs: 4 tokens per WAVE (vs 1) so each node_w float4 is loaded once and
// used 4x -> node_w L2 traffic 480->120 MB. FP order per token unchanged.
__global__ __launch_bounds__(256) void k_prep(
    const float* __restrict__ x, const float* __restrict__ node_w,
    const float* __restrict__ node_b, const float* __restrict__ w1,
    const float* __restrict__ w2, const float* __restrict__ b2,
    ushort_t* __restrict__ xb, float* __restrict__ probs,
    ushort_t* __restrict__ w1t, ushort_t* __restrict__ w2t,
    ushort_t* __restrict__ hp) {
  __shared__ ushort_t tile[64][68];
  const int b = blockIdx.x;
  if (b < 1024) {
    // w1t[l*256+h][k] = w1[l][k][h]
    const int tr = threadIdx.x >> 4, tc = (threadIdx.x & 15) * 4;
    const int l = b >> 6, rem = b & 63;
    const int kt = rem >> 2, ht = rem & 3;
    const float* in = w1 + (size_t)l * K1 * 256;
#pragma unroll
    for (int rr = 0; rr < 4; ++rr) {
      int r = tr + rr * 16;
      float4 v = *(const float4*)(in + (size_t)(kt * 64 + r) * 256 + ht * 64 + tc);
      tile[r][tc+0] = f2bf(v.x); tile[r][tc+1] = f2bf(v.y);
      tile[r][tc+2] = f2bf(v.z); tile[r][tc+3] = f2bf(v.w);
    }
    __syncthreads();
#pragma unroll
    for (int rr = 0; rr < 4; ++rr) {
      int oh = tr + rr * 16;
      ushort4 o;
      o.x = tile[tc+0][oh]; o.y = tile[tc+1][oh];
      o.z = tile[tc+2][oh]; o.w = tile[tc+3][oh];
      *(ushort4*)(w1t + (size_t)(l * 256 + ht * 64 + oh) * K1 + kt * 64 + tc) = o;
    }
  } else if (b < 2048) {
    // w2t[d][l*256+h] = w2[l][h][d]
    const int tr = threadIdx.x >> 4, tc = (threadIdx.x & 15) * 4;
    const int bb = b - 1024;
    const int l = bb >> 6, rem = bb & 63;
    const int ht = rem >> 4, dt = rem & 15;
    const float* in = w2 + (size_t)l * 256 * N2;
#pragma unroll
    for (int rr = 0; rr < 4; ++rr) {
      int r = tr + rr * 16;
      float4 v = *(const float4*)(in + (size_t)(ht * 64 + r) * N2 + dt * 64 + tc);
      tile[r][tc+0] = f2bf(v.x); tile[r][tc+1] = f2bf(v.y);
      tile[r][tc+2] = f2bf(v.z); tile[r][tc+3] = f2bf(v.w);
    }
    __syncthreads();
#pragma unroll
    for (int rr = 0; rr < 4; ++rr) {
      int od = tr + rr * 16;
      ushort4 o;
      o.x = tile[tc+0][od]; o.y = tile[tc+1][od];
      o.z = tile[tc+2][od]; o.w = tile[tc+3][od];
      *(ushort4*)(w2t + (size_t)(dt * 64 + od) * K2 + l * 256 + ht * 64 + tc) = o;
    }
  } else if (b < 2304) {
    int tid = (b - 2048) * 256 + threadIdx.x;   // 1024 * 64
    int d = tid >> 6, cc = tid & 63;
    float v = (cc < 16) ? b2[cc * N2 + d] : 0.f;
    w2t[(size_t)d * K2 + 4096 + cc] = f2bf(v);
  } else {
    // probs + x->bf16; 4 tokens per wave, 16 per block
    const int wid = threadIdx.x >> 6, lane = threadIdx.x & 63;
    const int t0 = (b - 2304) * 16 + wid * 4;
    float xv[4][16];
#pragma unroll
    for (int tt = 0; tt < 4; ++tt) {
      const float* xr = x + (size_t)(t0 + tt) * K1;
#pragma unroll
      for (int j = 0; j < 4; ++j) {
        float4 v = *(const float4*)(xr + j * 256 + lane * 4);
        xv[tt][4*j+0] = v.x; xv[tt][4*j+1] = v.y;
        xv[tt][4*j+2] = v.z; xv[tt][4*j+3] = v.w;
      }
      ushort_t* xbr = xb + (size_t)(t0 + tt) * K1;
#pragma unroll
      for (int j = 0; j < 4; ++j) {
        ushort4 o;
        o.x = f2bf(xv[tt][4*j+0]); o.y = f2bf(xv[tt][4*j+1]);
        o.z = f2bf(xv[tt][4*j+2]); o.w = f2bf(xv[tt][4*j+3]);
        *(ushort4*)(xbr + j * 256 + lane * 4) = o;
      }
    }
    float c[4][15];
#pragma unroll
    for (int n = 0; n < 15; ++n) {
      const float* wr = node_w + n * K1;
      float s0 = 0.f, s1 = 0.f, s2 = 0.f, s3 = 0.f;
#pragma unroll
      for (int j = 0; j < 4; ++j) {
        float4 w = *(const float4*)(wr + j * 256 + lane * 4);
        s0 += xv[0][4*j+0]*w.x + xv[0][4*j+1]*w.y + xv[0][4*j+2]*w.z + xv[0][4*j+3]*w.w;
        s1 += xv[1][4*j+0]*w.x + xv[1][4*j+1]*w.y + xv[1][4*j+2]*w.z + xv[1][4*j+3]*w.w;
        s2 += xv[2][4*j+0]*w.x + xv[2][4*j+1]*w.y + xv[2][4*j+2]*w.z + xv[2][4*j+3]*w.w;
        s3 += xv[3][4*j+0]*w.x + xv[3][4*j+1]*w.y + xv[3][4*j+2]*w.z + xv[3][4*j+3]*w.w;
      }
#pragma unroll
      for (int off = 32; off > 0; off >>= 1) {
        s0 += __shfl_xor(s0, off); s1 += __shfl_xor(s1, off);
        s2 += __shfl_xor(s2, off); s3 += __shfl_xor(s3, off);
      }
      float zb = node_b[n];
      c[0][n] = 1.f / (1.f + __expf(-(s0 + zb)));
      c[1][n] = 1.f / (1.f + __expf(-(s1 + zb)));
      c[2][n] = 1.f / (1.f + __expf(-(s2 + zb)));
      c[3][n] = 1.f / (1.f + __expf(-(s3 + zb)));
    }
    if (lane < 16) {
#pragma unroll
      for (int tt = 0; tt < 4; ++tt) {
        float p = 1.f;
#pragma unroll
        for (int m = 0; m < 4; ++m) {
          int jm = lane >> (4 - m);
          int node = (1 << m) - 1 + jm;
          int bit = (lane >> (3 - m)) & 1;
          p *= bit ? (1.f - c[tt][node]) : c[tt][node];
        }
        probs[(t0 + tt) * 16 + lane] = p;
        hp[(size_t)(t0 + tt) * K2 + 4096 + lane] = f2bf(p);
      }
    }
    if (lane < 48) {
#pragma unroll
      for (int tt = 0; tt < 4; ++tt)
        hp[(size_t)(t0 + tt) * K2 + 4112 + lane] = 0;
    }
  }
}

// ---------------- 256xBN MFMA GEMM, 2 barriers/K-tile, K-loop unroll x2 -----
// (round-6 verified config: GEMM1 72.8us, GEMM2 72.4us, conflicts 0)
template <int NT, int LDA, int LDB, int BN, int MODE>
__global__ __launch_bounds__(512, 2) void k_gemm8(
    const ushort_t* __restrict__ A, const ushort_t* __restrict__ Bt,
    const float* __restrict__ probs, const float* __restrict__ b1,
    ushort_t* __restrict__ hp, float* __restrict__ out, int ntn) {
  constexpr int BHR = BN / 2;                 // B half rows
  constexpr int WN = (BN == 256) ? 4 : 2;
  constexpr int WM = 8 / WN;
  constexpr int FH = 128 / (WM * 16);         // m-frags per half per wave
  constexpr int ABYTES = 128 * 128;
  constexpr int BBYTES = BHR * 128;
  constexpr int KEEP = 2 + 2 * (BHR / 64);    // region1 loads: A0 + B0 + B1

  extern __shared__ char lds[];
  const int tid = threadIdx.x;
  int bid = blockIdx.x;
  const int nwg = gridDim.x;                  // divisible by 8
  bid = (bid & 7) * (nwg >> 3) + (bid >> 3);  // XCD swizzle (bijective)
  const int bm = bid / ntn, bn = bid % ntn;

  const int wid = tid >> 6, lane = tid & 63;
  const int widM = wid / WN, widN = wid % WN;
  const int wmBase = widM * (FH * 16);
  const int wn = widN * 64;
  const int lr = lane & 15, g = lane >> 4;

  const ushort_t* Ag = A + (size_t)bm * 256 * LDA;
  const ushort_t* Bg = Bt + (size_t)bn * BN * LDB;

  const int srow = tid >> 3;
  const int scol = ((tid & 7) << 4) ^ ((srow & 7) << 4);

  const char* pA = (const char*)(Ag + (size_t)srow * LDA) + scol;
  const char* pB = (const char*)(Bg + (size_t)srow * LDB) + scol;

  auto stageA = [&](int buf, int half, int kt) {
    const char* src = pA + (size_t)(half * 128) * (LDA * 2) + kt * 128;
    char* dst = lds + (buf * 2 + half) * ABYTES + tid * 16;
#pragma unroll
    for (int r = 0; r < 2; ++r)
      gload16(src + (size_t)(r * 64) * (LDA * 2), dst + r * 8192);
  };
  auto stageB = [&](int buf, int half, int kt) {
    const char* src = pB + (size_t)(half * BHR) * (LDB * 2) + kt * 128;
    char* dst = lds + 4 * ABYTES + (buf * 2 + half) * BBYTES + tid * 16;
#pragma unroll
    for (int r = 0; r < BHR / 64; ++r)
      gload16(src + (size_t)(r * 64) * (LDB * 2), dst + r * 8192);
  };
  auto rdA = [&](int buf, int half, int i, int kk) -> bf16x8 {
    int r = wmBase + i * 16 + lr;
    int off = r * 128 + (((kk * 4 + g) ^ (lr & 7)) << 4);
    return *(const bf16x8*)(lds + (buf * 2 + half) * ABYTES + off);
  };
  auto rdB = [&](int buf, int j, int kk) -> bf16x8 {
    int nr = wn + j * 16;
    int half = (nr >= BHR) ? 1 : 0;
    int r = (nr & (BHR - 1)) + lr;
    int off = r * 128 + (((kk * 4 + g) ^ (lr & 7)) << 4);
    return *(const bf16x8*)(lds + 4 * ABYTES + (buf * 2 + half) * BBYTES + off);
  };

  f32x4 acc[2 * FH][4];
#pragma unroll
  for (int i = 0; i < 2 * FH; ++i)
#pragma unroll
    for (int j = 0; j < 4; ++j) acc[i][j] = (f32x4){0.f, 0.f, 0.f, 0.f};

  // prologue: buf0 full (oldest), then buf1 {A0,B0,B1}.
  stageA(0, 0, 0); stageA(0, 1, 0); stageB(0, 0, 0); stageB(0, 1, 0);
  stageA(1, 0, 1); stageB(1, 0, 1); stageB(1, 1, 1);
  if constexpr (KEEP == 6) asm volatile("s_waitcnt vmcnt(6)" ::: "memory");
  else                     asm volatile("s_waitcnt vmcnt(4)" ::: "memory");
  __builtin_amdgcn_sched_barrier(0);
  __builtin_amdgcn_s_barrier();
  __builtin_amdgcn_sched_barrier(0);

  auto body = [&](auto CURC, int kt) {
    constexpr int cur = decltype(CURC)::value;
    bf16x8 bfr[2][4];
    // ---------------- region 0 (A half 0, all B) ----------------
    {
      bf16x8 a0[FH][2];
#pragma unroll
      for (int kk = 0; kk < 2; ++kk) {
#pragma unroll
        for (int i = 0; i < FH; ++i) a0[i][kk] = rdA(cur, 0, i, kk);
#pragma unroll
        for (int j = 0; j < 4; ++j) bfr[kk][j] = rdB(cur, j, kk);
      }
      if (kt + 1 < NT) stageA(cur ^ 1, 1, kt + 1);
      __builtin_amdgcn_s_setprio(1);
#pragma unroll
      for (int kk = 0; kk < 2; ++kk)
#pragma unroll
        for (int j = 0; j < 4; ++j)
#pragma unroll
          for (int i = 0; i < FH; ++i)
            acc[i][j] = __builtin_amdgcn_mfma_f32_16x16x32_bf16(
                a0[i][kk], bfr[kk][j], acc[i][j], 0, 0, 0);
      __builtin_amdgcn_s_setprio(0);
    }
    __builtin_amdgcn_s_barrier();
    __builtin_amdgcn_sched_barrier(0);
    // ---------------- region 1 (A half 1, reuse bfr) ----------------
    {
      bf16x8 a1[FH][2];
#pragma unroll
      for (int kk = 0; kk < 2; ++kk)
#pragma unroll
        for (int i = 0; i < FH; ++i) a1[i][kk] = rdA(cur, 1, i, kk);
      if (kt + 2 < NT) {
        stageA(cur, 0, kt + 2);
        stageB(cur, 0, kt + 2);
        stageB(cur, 1, kt + 2);
      }
      __builtin_amdgcn_s_setprio(1);
#pragma unroll
      for (int kk = 0; kk < 2; ++kk)
#pragma unroll
        for (int j = 0; j < 4; ++j)
#pragma unroll
          for (int i = 0; i < FH; ++i)
            acc[FH + i][j] = __builtin_amdgcn_mfma_f32_16x16x32_bf16(
                a1[i][kk], bfr[kk][j], acc[FH + i][j], 0, 0, 0);
      __builtin_amdgcn_s_setprio(0);
    }
    if (kt + 2 < NT) {
      if constexpr (KEEP == 6) asm volatile("s_waitcnt vmcnt(6)" ::: "memory");
      else                     asm volatile("s_waitcnt vmcnt(4)" ::: "memory");
      __builtin_amdgcn_sched_barrier(0);
    } else if (kt + 1 < NT) {
      asm volatile("s_waitcnt vmcnt(0)" ::: "memory");
      __builtin_amdgcn_sched_barrier(0);
    }
    __builtin_amdgcn_s_barrier();
    __builtin_amdgcn_sched_barrier(0);
  };

  int kt = 0;
#pragma unroll 1
  for (int it = 0; it < NT / 2; ++it) {
    body(ic<0>{}, kt); ++kt;
    body(ic<1>{}, kt); ++kt;
  }
  if constexpr (NT & 1) body(ic<0>{}, kt);

  // epilogue: C/D layout col=lane&15, row=(lane>>4)*4+reg
  const int rowb = bm * 256 + wmBase + g * 4;
  const int colb = bn * BN + wn + lr;
  if (MODE == 0) {
    const int leaf = bn;   // BN=256 tile == one leaf
#pragma unroll
    for (int q = 0; q < 2; ++q)
#pragma unroll
      for (int i = 0; i < FH; ++i) {
        int rbase = rowb + q * 128 + i * 16;
        float pm[4];
#pragma unroll
        for (int rg = 0; rg < 4; ++rg)
          pm[rg] = probs[(size_t)(rbase + rg) * 16 + leaf];
#pragma unroll
        for (int j = 0; j < 4; ++j) {
          float bias = b1[colb + j * 16];
#pragma unroll
          for (int rg = 0; rg < 4; ++rg) {
            float v = acc[q * FH + i][j][rg] + bias;
            v = v > 0.f ? v : 0.f;
            v *= pm[rg];
            hp[(size_t)(rbase + rg) * K2 + colb + j * 16] = f2bf(v);
          }
        }
      }
  } else {
#pragma unroll
    for (int q = 0; q < 2; ++q)
#pragma unroll
      for (int i = 0; i < FH; ++i) {
        int rbase = rowb + q * 128 + i * 16;
#pragma unroll
        for (int j = 0; j < 4; ++j)
#pragma unroll
          for (int rg = 0; rg < 4; ++rg)
            out[(size_t)(rbase + rg) * N2 + colb + j * 16] = acc[q * FH + i][j][rg];
      }
  }
}

extern "C" void kernel_launch(void* const* d_in, const int* in_sizes, int n_in,
                              void* d_out, int out_size, void* d_ws, size_t ws_size,
                              hipStream_t stream) {
  const float* x      = (const float*)d_in[0];
  const float* node_w = (const float*)d_in[1];
  const float* node_b = (const float*)d_in[2];
  const float* w1     = (const float*)d_in[3];
  const float* b1     = (const float*)d_in[4];
  const float* w2     = (const float*)d_in[5];
  const float* b2     = (const float*)d_in[6];
  float* out = (float*)d_out;

  char* ws = (char*)d_ws;
  ushort_t* xb    = (ushort_t*)(ws);
  ushort_t* w1t   = (ushort_t*)(ws + 16777216);
  ushort_t* w2t   = (ushort_t*)(ws + 25165824);
  ushort_t* hp    = (ushort_t*)(ws + 33685504);
  float*    probs = (float*)   (ws + 101842944);

  k_prep<<<2816, 256, 0, stream>>>(x, node_w, node_b, w1, w2, b2,
                                   xb, probs, w1t, w2t, hp);
  // GEMM1: 8192x4096, K=1024: 32x16=512 blocks, BN=256, LDS 128 KiB
  k_gemm8<16, K1, K1, 256, 0><<<512, 512, 131072, stream>>>(
      xb, w1t, probs, b1, hp, nullptr, N1 / 256);
  // GEMM2: 8192x1024, K=4160: 32x8=256 blocks, BN=128, LDS 96 KiB
  k_gemm8<65, K2, K2, 128, 1><<<256, 512, 98304, stream>>>(
      hp, w2t, nullptr, nullptr, nullptr, out, N2 / 128);
}

// Round 13
// 169.020 us; speedup vs baseline: 1.0381x; 1.0381x over previous
//
#include <hip/hip_runtime.h>
#include <stdint.h>

typedef unsigned short ushort_t;
typedef __bf16 bf16x8 __attribute__((ext_vector_type(8)));
typedef float f32x4 __attribute__((ext_vector_type(4)));

#define M_TOK 8192
#define K1 1024
#define N1 4096
#define K2 4160   /* 4096 (h) + 16 (probs/b2) + 48 zero-pad -> 65 K-steps of 64 */
#define N2 1024

template <int V> struct ic { static constexpr int value = V; };

__device__ __forceinline__ ushort_t f2bf(float f) {
  union { float f; unsigned u; } v; v.f = f;
  unsigned u = v.u;
  u += 0x7FFFu + ((u >> 16) & 1u);   // RNE; inputs finite
  return (ushort_t)(u >> 16);
}

__device__ __forceinline__ void gload16(const void* g, void* l) {
  __builtin_amdgcn_global_load_lds((__attribute__((address_space(1))) void*)g,
                                   (__attribute__((address_space(3))) void*)l,
                                   16, 0, 0);
}

// ---------------- merged prep: wprep (blocks 0..2303) + probs (2304..4351) --
__global__ __launch_bounds__(256) void k_prep(
    const float* __restrict__ x, const float* __restrict__ node_w,
    const float* __restrict__ node_b, const float* __restrict__ w1,
    const float* __restrict__ w2, const float* __restrict__ b2,
    ushort_t* __restrict__ xb, float* __restrict__ probs,
    ushort_t* __restrict__ w1t, ushort_t* __restrict__ w2t,
    ushort_t* __restrict__ hp) {
  __shared__ ushort_t tile[64][68];
  const int b = blockIdx.x;
  if (b < 1024) {
    // w1t[l*256+h][k] = w1[l][k][h]
    const int tr = threadIdx.x >> 4, tc = (threadIdx.x & 15) * 4;
    const int l = b >> 6, rem = b & 63;
    const int kt = rem >> 2, ht = rem & 3;
    const float* in = w1 + (size_t)l * K1 * 256;
#pragma unroll
    for (int rr = 0; rr < 4; ++rr) {
      int r = tr + rr * 16;
      float4 v = *(const float4*)(in + (size_t)(kt * 64 + r) * 256 + ht * 64 + tc);
      tile[r][tc+0] = f2bf(v.x); tile[r][tc+1] = f2bf(v.y);
      tile[r][tc+2] = f2bf(v.z); tile[r][tc+3] = f2bf(v.w);
    }
    __syncthreads();
#pragma unroll
    for (int rr = 0; rr < 4; ++rr) {
      int oh = tr + rr * 16;
      ushort4 o;
      o.x = tile[tc+0][oh]; o.y = tile[tc+1][oh];
      o.z = tile[tc+2][oh]; o.w = tile[tc+3][oh];
      *(ushort4*)(w1t + (size_t)(l * 256 + ht * 64 + oh) * K1 + kt * 64 + tc) = o;
    }
  } else if (b < 2048) {
    // w2t[d][l*256+h] = w2[l][h][d]
    const int tr = threadIdx.x >> 4, tc = (threadIdx.x & 15) * 4;
    const int bb = b - 1024;
    const int l = bb >> 6, rem = bb & 63;
    const int ht = rem >> 4, dt = rem & 15;
    const float* in = w2 + (size_t)l * 256 * N2;
#pragma unroll
    for (int rr = 0; rr < 4; ++rr) {
      int r = tr + rr * 16;
      float4 v = *(const float4*)(in + (size_t)(ht * 64 + r) * N2 + dt * 64 + tc);
      tile[r][tc+0] = f2bf(v.x); tile[r][tc+1] = f2bf(v.y);
      tile[r][tc+2] = f2bf(v.z); tile[r][tc+3] = f2bf(v.w);
    }
    __syncthreads();
#pragma unroll
    for (int rr = 0; rr < 4; ++rr) {
      int od = tr + rr * 16;
      ushort4 o;
      o.x = tile[tc+0][od]; o.y = tile[tc+1][od];
      o.z = tile[tc+2][od]; o.w = tile[tc+3][od];
      *(ushort4*)(w2t + (size_t)(dt * 64 + od) * K2 + l * 256 + ht * 64 + tc) = o;
    }
  } else if (b < 2304) {
    int tid = (b - 2048) * 256 + threadIdx.x;   // 1024 * 64
    int d = tid >> 6, cc = tid & 63;
    float v = (cc < 16) ? b2[cc * N2 + d] : 0.f;
    w2t[(size_t)d * K2 + 4096 + cc] = f2bf(v);
  } else {
    // probs + x->bf16; 1 wave per token
    const int wid = threadIdx.x >> 6, lane = threadIdx.x & 63;
    const int t = (b - 2304) * 4 + wid;
    const float* xr = x + (size_t)t * K1;
    float xv[16];
#pragma unroll
    for (int j = 0; j < 4; ++j) {
      float4 v = *(const float4*)(xr + j * 256 + lane * 4);
      xv[4*j+0] = v.x; xv[4*j+1] = v.y; xv[4*j+2] = v.z; xv[4*j+3] = v.w;
    }
    ushort_t* xbr = xb + (size_t)t * K1;
#pragma unroll
    for (int j = 0; j < 4; ++j) {
      ushort4 o;
      o.x = f2bf(xv[4*j+0]); o.y = f2bf(xv[4*j+1]);
      o.z = f2bf(xv[4*j+2]); o.w = f2bf(xv[4*j+3]);
      *(ushort4*)(xbr + j * 256 + lane * 4) = o;
    }
    float c[15];
#pragma unroll
    for (int n = 0; n < 15; ++n) {
      float s = 0.f;
      const float* wr = node_w + n * K1;
#pragma unroll
      for (int j = 0; j < 4; ++j) {
        float4 w = *(const float4*)(wr + j * 256 + lane * 4);
        s += xv[4*j+0]*w.x + xv[4*j+1]*w.y + xv[4*j+2]*w.z + xv[4*j+3]*w.w;
      }
#pragma unroll
      for (int off = 32; off > 0; off >>= 1) s += __shfl_xor(s, off);
      float z = s + node_b[n];
      c[n] = 1.f / (1.f + __expf(-z));
    }
    if (lane < 16) {
      float p = 1.f;
#pragma unroll
      for (int m = 0; m < 4; ++m) {
        int jm = lane >> (4 - m);
        int node = (1 << m) - 1 + jm;
        int bit = (lane >> (3 - m)) & 1;
        p *= bit ? (1.f - c[node]) : c[node];
      }
      probs[t * 16 + lane] = p;
      hp[(size_t)t * K2 + 4096 + lane] = f2bf(p);
    }
    if (lane < 48) hp[(size_t)t * K2 + 4112 + lane] = 0;
  }
}

// ---------------- 256xBN MFMA GEMM, 2 barriers/K-tile, K-loop unroll x2 -----
// (verified best: GEMM1 72.8us, GEMM2 72.4us, conflicts 0, ~940-960 TF)
template <int NT, int LDA, int LDB, int BN, int MODE>
__global__ __launch_bounds__(512, 2) void k_gemm8(
    const ushort_t* __restrict__ A, const ushort_t* __restrict__ Bt,
    const float* __restrict__ probs, const float* __restrict__ b1,
    ushort_t* __restrict__ hp, float* __restrict__ out, int ntn) {
  constexpr int BHR = BN / 2;                 // B half rows
  constexpr int WN = (BN == 256) ? 4 : 2;
  constexpr int WM = 8 / WN;
  constexpr int FH = 128 / (WM * 16);         // m-frags per half per wave
  constexpr int ABYTES = 128 * 128;
  constexpr int BBYTES = BHR * 128;
  constexpr int KEEP = 2 + 2 * (BHR / 64);    // region1 loads: A0 + B0 + B1

  extern __shared__ char lds[];
  const int tid = threadIdx.x;
  int bid = blockIdx.x;
  const int nwg = gridDim.x;                  // divisible by 8
  bid = (bid & 7) * (nwg >> 3) + (bid >> 3);  // XCD swizzle (bijective)
  const int bm = bid / ntn, bn = bid % ntn;

  const int wid = tid >> 6, lane = tid & 63;
  const int widM = wid / WN, widN = wid % WN;
  const int wmBase = widM * (FH * 16);
  const int wn = widN * 64;
  const int lr = lane & 15, g = lane >> 4;

  const ushort_t* Ag = A + (size_t)bm * 256 * LDA;
  const ushort_t* Bg = Bt + (size_t)bn * BN * LDB;

  const int srow = tid >> 3;
  const int scol = ((tid & 7) << 4) ^ ((srow & 7) << 4);

  const char* pA = (const char*)(Ag + (size_t)srow * LDA) + scol;
  const char* pB = (const char*)(Bg + (size_t)srow * LDB) + scol;

  auto stageA = [&](int buf, int half, int kt) {
    const char* src = pA + (size_t)(half * 128) * (LDA * 2) + kt * 128;
    char* dst = lds + (buf * 2 + half) * ABYTES + tid * 16;
#pragma unroll
    for (int r = 0; r < 2; ++r)
      gload16(src + (size_t)(r * 64) * (LDA * 2), dst + r * 8192);
  };
  auto stageB = [&](int buf, int half, int kt) {
    const char* src = pB + (size_t)(half * BHR) * (LDB * 2) + kt * 128;
    char* dst = lds + 4 * ABYTES + (buf * 2 + half) * BBYTES + tid * 16;
#pragma unroll
    for (int r = 0; r < BHR / 64; ++r)
      gload16(src + (size_t)(r * 64) * (LDB * 2), dst + r * 8192);
  };
  auto rdA = [&](int buf, int half, int i, int kk) -> bf16x8 {
    int r = wmBase + i * 16 + lr;
    int off = r * 128 + (((kk * 4 + g) ^ (lr & 7)) << 4);
    return *(const bf16x8*)(lds + (buf * 2 + half) * ABYTES + off);
  };
  auto rdB = [&](int buf, int j, int kk) -> bf16x8 {
    int nr = wn + j * 16;
    int half = (nr >= BHR) ? 1 : 0;
    int r = (nr & (BHR - 1)) + lr;
    int off = r * 128 + (((kk * 4 + g) ^ (lr & 7)) << 4);
    return *(const bf16x8*)(lds + 4 * ABYTES + (buf * 2 + half) * BBYTES + off);
  };

  f32x4 acc[2 * FH][4];
#pragma unroll
  for (int i = 0; i < 2 * FH; ++i)
#pragma unroll
    for (int j = 0; j < 4; ++j) acc[i][j] = (f32x4){0.f, 0.f, 0.f, 0.f};

  // prologue: buf0 full (oldest), then buf1 {A0,B0,B1}.
  stageA(0, 0, 0); stageA(0, 1, 0); stageB(0, 0, 0); stageB(0, 1, 0);
  stageA(1, 0, 1); stageB(1, 0, 1); stageB(1, 1, 1);
  if constexpr (KEEP == 6) asm volatile("s_waitcnt vmcnt(6)" ::: "memory");
  else                     asm volatile("s_waitcnt vmcnt(4)" ::: "memory");
  __builtin_amdgcn_sched_barrier(0);
  __builtin_amdgcn_s_barrier();
  __builtin_amdgcn_sched_barrier(0);

  auto body = [&](auto CURC, int kt) {
    constexpr int cur = decltype(CURC)::value;
    bf16x8 bfr[2][4];
    // ---------------- region 0 (A half 0, all B) ----------------
    {
      bf16x8 a0[FH][2];
#pragma unroll
      for (int kk = 0; kk < 2; ++kk) {
#pragma unroll
        for (int i = 0; i < FH; ++i) a0[i][kk] = rdA(cur, 0, i, kk);
#pragma unroll
        for (int j = 0; j < 4; ++j) bfr[kk][j] = rdB(cur, j, kk);
      }
      if (kt + 1 < NT) stageA(cur ^ 1, 1, kt + 1);
      __builtin_amdgcn_s_setprio(1);
#pragma unroll
      for (int kk = 0; kk < 2; ++kk)
#pragma unroll
        for (int j = 0; j < 4; ++j)
#pragma unroll
          for (int i = 0; i < FH; ++i)
            acc[i][j] = __builtin_amdgcn_mfma_f32_16x16x32_bf16(
                a0[i][kk], bfr[kk][j], acc[i][j], 0, 0, 0);
      __builtin_amdgcn_s_setprio(0);
    }
    __builtin_amdgcn_s_barrier();
    __builtin_amdgcn_sched_barrier(0);
    // ---------------- region 1 (A half 1, reuse bfr) ----------------
    {
      bf16x8 a1[FH][2];
#pragma unroll
      for (int kk = 0; kk < 2; ++kk)
#pragma unroll
        for (int i = 0; i < FH; ++i) a1[i][kk] = rdA(cur, 1, i, kk);
      if (kt + 2 < NT) {
        stageA(cur, 0, kt + 2);
        stageB(cur, 0, kt + 2);
        stageB(cur, 1, kt + 2);
      }
      __builtin_amdgcn_s_setprio(1);
#pragma unroll
      for (int kk = 0; kk < 2; ++kk)
#pragma unroll
        for (int j = 0; j < 4; ++j)
#pragma unroll
          for (int i = 0; i < FH; ++i)
            acc[FH + i][j] = __builtin_amdgcn_mfma_f32_16x16x32_bf16(
                a1[i][kk], bfr[kk][j], acc[FH + i][j], 0, 0, 0);
      __builtin_amdgcn_s_setprio(0);
    }
    if (kt + 2 < NT) {
      if constexpr (KEEP == 6) asm volatile("s_waitcnt vmcnt(6)" ::: "memory");
      else                     asm volatile("s_waitcnt vmcnt(4)" ::: "memory");
      __builtin_amdgcn_sched_barrier(0);
    } else if (kt + 1 < NT) {
      asm volatile("s_waitcnt vmcnt(0)" ::: "memory");
      __builtin_amdgcn_sched_barrier(0);
    }
    __builtin_amdgcn_s_barrier();
    __builtin_amdgcn_sched_barrier(0);
  };

  int kt = 0;
#pragma unroll 1
  for (int it = 0; it < NT / 2; ++it) {
    body(ic<0>{}, kt); ++kt;
    body(ic<1>{}, kt); ++kt;
  }
  if constexpr (NT & 1) body(ic<0>{}, kt);

  // epilogue: C/D layout col=lane&15, row=(lane>>4)*4+reg
  const int rowb = bm * 256 + wmBase + g * 4;
  const int colb = bn * BN + wn + lr;
  if (MODE == 0) {
    const int leaf = bn;   // BN=256 tile == one leaf
#pragma unroll
    for (int q = 0; q < 2; ++q)
#pragma unroll
      for (int i = 0; i < FH; ++i) {
        int rbase = rowb + q * 128 + i * 16;
        float pm[4];
#pragma unroll
        for (int rg = 0; rg < 4; ++rg)
          pm[rg] = probs[(size_t)(rbase + rg) * 16 + leaf];
#pragma unroll
        for (int j = 0; j < 4; ++j) {
          float bias = b1[colb + j * 16];
#pragma unroll
          for (int rg = 0; rg < 4; ++rg) {
            float v = acc[q * FH + i][j][rg] + bias;
            v = v > 0.f ? v : 0.f;
            v *= pm[rg];
            hp[(size_t)(rbase + rg) * K2 + colb + j * 16] = f2bf(v);
          }
        }
      }
  } else {
#pragma unroll
    for (int q = 0; q < 2; ++q)
#pragma unroll
      for (int i = 0; i < FH; ++i) {
        int rbase = rowb + q * 128 + i * 16;
#pragma unroll
        for (int j = 0; j < 4; ++j)
#pragma unroll
          for (int rg = 0; rg < 4; ++rg)
            out[(size_t)(rbase + rg) * N2 + colb + j * 16] = acc[q * FH + i][j][rg];
      }
  }
}

extern "C" void kernel_launch(void* const* d_in, const int* in_sizes, int n_in,
                              void* d_out, int out_size, void* d_ws, size_t ws_size,
                              hipStream_t stream) {
  const float* x      = (const float*)d_in[0];
  const float* node_w = (const float*)d_in[1];
  const float* node_b = (const float*)d_in[2];
  const float* w1     = (const float*)d_in[3];
  const float* b1     = (const float*)d_in[4];
  const float* w2     = (const float*)d_in[5];
  const float* b2     = (const float*)d_in[6];
  float* out = (float*)d_out;

  char* ws = (char*)d_ws;
  ushort_t* xb    = (ushort_t*)(ws);
  ushort_t* w1t   = (ushort_t*)(ws + 16777216);
  ushort_t* w2t   = (ushort_t*)(ws + 25165824);
  ushort_t* hp    = (ushort_t*)(ws + 33685504);
  float*    probs = (float*)   (ws + 101842944);

  k_prep<<<4352, 256, 0, stream>>>(x, node_w, node_b, w1, w2, b2,
                                   xb, probs, w1t, w2t, hp);
  // GEMM1: 8192x4096, K=1024: 32x16=512 blocks, BN=256, LDS 128 KiB
  k_gemm8<16, K1, K1, 256, 0><<<512, 512, 131072, stream>>>(
      xb, w1t, probs, b1, hp, nullptr, N1 / 256);
  // GEMM2: 8192x1024, K=4160: 32x8=256 blocks, BN=128, LDS 96 KiB
  k_gemm8<65, K2, K2, 128, 1><<<256, 512, 98304, stream>>>(
      hp, w2t, nullptr, nullptr, nullptr, out, N2 / 128);
}